// Round 1
// baseline (7979.198 us; speedup 1.0000x reference)
//
#include <hip/hip_runtime.h>
#include <math.h>

// ---------------- problem constants ----------------
static constexpr int B_ = 4, S_ = 2048, D_ = 1024, CH_ = 64, N_ = 32;
static constexpr float EPS_ = 1.1920929e-07f;          // torch fp32 eps
static constexpr float C2_  = 2.0f / 262144.0f;        // 2 / (B*CH*D)

#define TK 16
#define TM 64
#define TN 64

__device__ __forceinline__ float sigf(float x)  { return 1.f/(1.f+expf(-x)); }
__device__ __forceinline__ float siluf(float x) { return x/(1.f+expf(-x)); }
__device__ __forceinline__ float silugrad(float x){
  float s = 1.f/(1.f+expf(-x));
  return s*(1.f + x*(1.f-s));
}

// ---------------- epilogue functors ----------------
struct EpiStore { float* C;
  __device__ void operator()(int r,int c,float v) const { C[(size_t)r*D_+c]=v; } };

struct EpiBiasSig { float* C; const float* bias;
  __device__ void operator()(int r,int c,float v) const {
    C[(size_t)r*D_+c] = sigf(v + bias[c]); } };

// scatter rows (b*S+s) -> chunk-major layout; part: -1 = v [N,256,D], 0 = q rows, 1 = k rows of qk [N,512,D]
struct EpiSiluScatter { float* dst; int part;
  __device__ void operator()(int r,int c,float v) const {
    int b = r >> 11, s = r & 2047, t = s >> 6, ch = s & 63;
    float sv = siluf(v);
    if (part < 0) dst[((size_t)t*256 +             b*64 + ch)*D_ + c] = sv;
    else          dst[((size_t)t*512 + part*256 + b*64 + ch)*D_ + c] = sv;
  } };

struct EpiHA { float* H; float* A2;   // write pre-act and silu(act)
  __device__ void operator()(int r,int c,float v) const {
    size_t i=(size_t)r*D_+c; H[i]=v; A2[i]=siluf(v); } };

// rows<256: retrieved r -> preout[b, t*CH+ch, :]; rows>=256: dpred = C2*(pred - v)
struct EpiRetr { float* preout; const float* Vt; float* dpred; int t;
  __device__ void operator()(int r,int c,float v) const {
    if (r < 256) { int b=r>>6, ch=r&63;
      preout[((size_t)b*S_ + t*CH_ + ch)*D_ + c] = v; }
    else { size_t i=(size_t)(r-256)*D_+c; dpred[i] = C2_*(v - Vt[i]); }
  } };

struct EpiDH { float* dh; const float* Hk;
  __device__ void operator()(int r,int c,float v) const {
    size_t i=(size_t)r*D_+c; dh[i] = v * silugrad(Hk[i]); } };

// g -> momentum + decayed weight update (Eq. 13/14), fused
struct EpiUpd { float* W; float* Sm; const float* gates; int t;
  __device__ void operator()(int r,int c,float v) const {
    float al=gates[t], th=gates[N_+t], et=gates[2*N_+t];
    size_t i=(size_t)r*D_+c;
    float s = et*Sm[i] - th*v;
    Sm[i] = s;
    W[i]  = (1.f-al)*W[i] + s;
  } };

#define FMA16 \
  acc[0][0]+=a4.x*b4.x; acc[0][1]+=a4.x*b4.y; acc[0][2]+=a4.x*b4.z; acc[0][3]+=a4.x*b4.w; \
  acc[1][0]+=a4.y*b4.x; acc[1][1]+=a4.y*b4.y; acc[1][2]+=a4.y*b4.z; acc[1][3]+=a4.y*b4.w; \
  acc[2][0]+=a4.z*b4.x; acc[2][1]+=a4.z*b4.y; acc[2][2]+=a4.z*b4.z; acc[2][3]+=a4.z*b4.w; \
  acc[3][0]+=a4.w*b4.x; acc[3][1]+=a4.w*b4.y; acc[3][2]+=a4.w*b4.z; acc[3][3]+=a4.w*b4.w;

// ---------------- GEMM: C[M,N] = A[M,K] @ B[N,K]^T ----------------
template<class Epi>
__global__ __launch_bounds__(256)
void gemm_nt_k(const float* __restrict__ A, const float* __restrict__ Bm, int K, Epi epi){
  __shared__ __align__(16) float As[TK][TM+4];
  __shared__ __align__(16) float Bs[TK][TN+4];
  const int bm = blockIdx.y*TM, bn = blockIdx.x*TN;
  const int tid = threadIdx.x, tx = tid&15, ty = tid>>4;
  const int lrow = tid>>2, lk = (tid&3)<<2;
  const float* Ap = A  + (size_t)(bm+lrow)*K + lk;
  const float* Bp = Bm + (size_t)(bn+lrow)*K + lk;
  float acc[4][4] = {};
  for (int k0=0;k0<K;k0+=TK){
    float4 av = *(const float4*)(Ap + k0);
    float4 bv = *(const float4*)(Bp + k0);
    __syncthreads();
    As[lk+0][lrow]=av.x; As[lk+1][lrow]=av.y; As[lk+2][lrow]=av.z; As[lk+3][lrow]=av.w;
    Bs[lk+0][lrow]=bv.x; Bs[lk+1][lrow]=bv.y; Bs[lk+2][lrow]=bv.z; Bs[lk+3][lrow]=bv.w;
    __syncthreads();
    #pragma unroll
    for (int kk=0;kk<TK;++kk){
      float4 a4 = *(const float4*)&As[kk][ty<<2];
      float4 b4 = *(const float4*)&Bs[kk][tx<<2];
      FMA16
    }
  }
  #pragma unroll
  for (int i=0;i<4;++i)
    #pragma unroll
    for (int j=0;j<4;++j)
      epi(bm+(ty<<2)+i, bn+(tx<<2)+j, acc[i][j]);
}

// ---------------- GEMM: C[M,N] = A[M,K] @ B[K,N] ----------------
template<class Epi>
__global__ __launch_bounds__(256)
void gemm_nn_k(const float* __restrict__ A, const float* __restrict__ Bm, int K, int ldb, Epi epi){
  __shared__ __align__(16) float As[TK][TM+4];
  __shared__ __align__(16) float Bs[TK][TN+4];
  const int bm = blockIdx.y*TM, bn = blockIdx.x*TN;
  const int tid = threadIdx.x, tx = tid&15, ty = tid>>4;
  const int larow = tid>>2, lak = (tid&3)<<2;
  const int lbrow = tid>>4, lbc = (tid&15)<<2;
  float acc[4][4] = {};
  for (int k0=0;k0<K;k0+=TK){
    float4 av = *(const float4*)(A  + (size_t)(bm+larow)*K + k0+lak);
    float4 bv = *(const float4*)(Bm + (size_t)(k0+lbrow)*ldb + bn + lbc);
    __syncthreads();
    As[lak+0][larow]=av.x; As[lak+1][larow]=av.y; As[lak+2][larow]=av.z; As[lak+3][larow]=av.w;
    *(float4*)&Bs[lbrow][lbc] = bv;
    __syncthreads();
    #pragma unroll
    for (int kk=0;kk<TK;++kk){
      float4 a4 = *(const float4*)&As[kk][ty<<2];
      float4 b4 = *(const float4*)&Bs[kk][tx<<2];
      FMA16
    }
  }
  #pragma unroll
  for (int i=0;i<4;++i)
    #pragma unroll
    for (int j=0;j<4;++j)
      epi(bm+(ty<<2)+i, bn+(tx<<2)+j, acc[i][j]);
}

// ---------------- GEMM: C[M,N] = A[K,M]^T @ B[K,N] ----------------
template<class Epi>
__global__ __launch_bounds__(256)
void gemm_tn_k(const float* __restrict__ A, const float* __restrict__ Bm, int K, int lda, int ldb, Epi epi){
  __shared__ __align__(16) float As[TK][TM+4];
  __shared__ __align__(16) float Bs[TK][TN+4];
  const int bm = blockIdx.y*TM, bn = blockIdx.x*TN;
  const int tid = threadIdx.x, tx = tid&15, ty = tid>>4;
  const int lrow = tid>>4, lc = (tid&15)<<2;
  float acc[4][4] = {};
  for (int k0=0;k0<K;k0+=TK){
    float4 av = *(const float4*)(A  + (size_t)(k0+lrow)*lda + bm + lc);
    float4 bv = *(const float4*)(Bm + (size_t)(k0+lrow)*ldb + bn + lc);
    __syncthreads();
    *(float4*)&As[lrow][lc] = av;
    *(float4*)&Bs[lrow][lc] = bv;
    __syncthreads();
    #pragma unroll
    for (int kk=0;kk<TK;++kk){
      float4 a4 = *(const float4*)&As[kk][ty<<2];
      float4 b4 = *(const float4*)&Bs[kk][tx<<2];
      FMA16
    }
  }
  #pragma unroll
  for (int i=0;i<4;++i)
    #pragma unroll
    for (int j=0;j<4;++j)
      epi(bm+(ty<<2)+i, bn+(tx<<2)+j, acc[i][j]);
}

// ---------------- small kernels ----------------
__device__ __forceinline__ float block_sum(float v){
  #pragma unroll
  for (int o=32;o>0;o>>=1) v += __shfl_down(v,o,64);
  __shared__ float sm4[4];
  int lane = threadIdx.x & 63, w = threadIdx.x >> 6;
  if (lane==0) sm4[w]=v;
  __syncthreads();
  float r = sm4[0]+sm4[1]+sm4[2]+sm4[3];
  __syncthreads();
  return r;
}

__global__ void chunk_mean_k(const float* __restrict__ x, float* __restrict__ cm){
  int idx = blockIdx.x*256 + threadIdx.x;       // over B*N*D = 131072
  int d  = idx & (D_-1);
  int bn = idx >> 10;                            // b*N+n
  int b = bn >> 5, n = bn & 31;
  const float* p = x + ((size_t)b*S_ + n*CH_)*D_ + d;
  float s = 0.f;
  for (int ch=0; ch<CH_; ++ch) s += p[(size_t)ch*D_];
  cm[idx] = s * (1.f/CH_);
}

__global__ void gate_reduce_k(const float* __restrict__ Z, float* __restrict__ outp, float scale){
  int n = blockIdx.x;
  float s = 0.f;
  for (int b=0;b<B_;++b){
    const float* row = Z + (size_t)(b*N_+n)*D_;
    for (int j=threadIdx.x; j<D_; j+=256) s += row[j];
  }
  float tot = block_sum(s);
  if (threadIdx.x==0) outp[n] = scale * tot / (float)(B_*D_);
}

__global__ void rmsnorm2_k(const float* __restrict__ x, const float* __restrict__ gs,
                           const float* __restrict__ gr, float* __restrict__ xs, float* __restrict__ xr){
  size_t row = blockIdx.x;
  const float* xp = x + row*D_;
  float s = 0.f;
  for (int j=threadIdx.x;j<D_;j+=256){ float v=xp[j]; s+=v*v; }
  float tot = block_sum(s);
  float rinv = rsqrtf(tot/(float)D_ + EPS_);
  for (int j=threadIdx.x;j<D_;j+=256){
    float v = xp[j]*rinv;
    xs[row*D_+j] = v*gs[j];
    xr[row*D_+j] = v*gr[j];
  }
}

__global__ void l2norm_k(float* __restrict__ qk){
  size_t row = blockIdx.x;
  float* p = qk + row*D_;
  float s = 0.f;
  for (int j=threadIdx.x;j<D_;j+=256){ float v=p[j]; s+=v*v; }
  float tot = block_sum(s);
  float inv = 1.f / fmaxf(sqrtf(tot), 1e-12f);
  for (int j=threadIdx.x;j<D_;j+=256) p[j] *= inv;
}

__global__ void init_state_k(const float* __restrict__ W0, const float* __restrict__ W1,
                             float* __restrict__ W0c, float* __restrict__ W1c,
                             float* __restrict__ S0, float* __restrict__ S1){
  size_t i = (size_t)blockIdx.x*256 + threadIdx.x;   // over 1048576
  W0c[i]=W0[i]; W1c[i]=W1[i]; S0[i]=0.f; S1[i]=0.f;
}

// ---------------- host ----------------
extern "C" void kernel_launch(void* const* d_in, const int* in_sizes, int n_in,
                              void* d_out, int out_size, void* d_ws, size_t ws_size,
                              hipStream_t stream) {
  (void)in_sizes; (void)n_in; (void)out_size;
  const float* x    = (const float*)d_in[0];
  const float* Mmet = (const float*)d_in[1];
  const float* Wk   = (const float*)d_in[2];
  const float* Wv   = (const float*)d_in[3];
  const float* Wq   = (const float*)d_in[4];
  const float* Wo   = (const float*)d_in[5];
  const float* Wgd  = (const float*)d_in[6];
  const float* bgd  = (const float*)d_in[7];
  const float* Wgl  = (const float*)d_in[8];
  const float* bgl  = (const float*)d_in[9];
  const float* Wgm  = (const float*)d_in[10];
  const float* bgm  = (const float*)d_in[11];
  const float* g_store = (const float*)d_in[12];
  const float* g_retr  = (const float*)d_in[13];
  const float* W0   = (const float*)d_in[14];
  const float* W1   = (const float*)d_in[15];
  float* out = (float*)d_out;

  // workspace layout (floats); total 50,331,776 floats = 201.3 MB
  if (ws_size < 50331904ull*sizeof(float)) return;   // insufficient scratch -> bench will flag
  float* ws   = (float*)d_ws;
  float* qk   = ws;                       // [N,512,D]  (q rows 0..255, k rows 256..511 per chunk)
  float* vbuf = qk  + 16777216;           // [N,256,D]
  float* xs   = vbuf + 8388608;           // [B*S,D]   -> reused as preout during scan
  float* xr   = xs  + 8388608;            // [B*S,D]   -> reused as scan scratch
  float* t1   = xr  + 8388608;            // [B*S,D]   -> reused as weight state
  float* gates= t1  + 8388608;            // [96]
  // temporal aliases
  float* cm    = vbuf;                    // [128,1024]   (dead before v written)
  float* Zg    = vbuf + 131072;           // [128,1024]
  float* preout= xs;
  float* h     = xr;                      // [512,1024]
  float* a     = xr + 524288;             // [512,1024]
  float* dpred = xr + 1048576;            // [256,1024]
  float* dh1   = xr + 1310720;            // [256,1024]
  float* W0c   = t1;                      // [1024,1024] each
  float* W1c   = t1 + 1048576;
  float* S0m   = t1 + 2097152;
  float* S1m   = t1 + 3145728;

  // P1: chunk means
  chunk_mean_k<<<512,256,0,stream>>>(x, cm);
  // P2: gates (alpha, theta, eta)
  {
    dim3 g(D_/TN, 128/TM);
    gemm_nt_k<EpiBiasSig><<<g,256,0,stream>>>(cm, Wgd, D_, EpiBiasSig{Zg, bgd});
    gate_reduce_k<<<N_,256,0,stream>>>(Zg, gates + 0,    0.01f);   // MEM_DECAY
    gemm_nt_k<EpiBiasSig><<<g,256,0,stream>>>(cm, Wgl, D_, EpiBiasSig{Zg, bgl});
    gate_reduce_k<<<N_,256,0,stream>>>(Zg, gates + N_,   0.1f);    // MEM_LR
    gemm_nt_k<EpiBiasSig><<<g,256,0,stream>>>(cm, Wgm, D_, EpiBiasSig{Zg, bgm});
    gate_reduce_k<<<N_,256,0,stream>>>(Zg, gates + 2*N_, 0.9f);    // MEM_MOM
  }
  // P3: dual RMSNorm
  rmsnorm2_k<<<B_*S_,256,0,stream>>>(x, g_store, g_retr, xs, xr);
  // P4: t1 = xs @ Mmet[b]  (nn, per batch)
  for (int b=0;b<B_;++b){
    gemm_nn_k<EpiStore><<<dim3(D_/TN, S_/TM),256,0,stream>>>(
      xs + (size_t)b*S_*D_, Mmet + (size_t)b*D_*D_, D_, D_, EpiStore{t1 + (size_t)b*S_*D_});
  }
  // P5/P6/P7: k, v, q with silu + chunk scatter
  {
    dim3 g(D_/TN, (B_*S_)/TM);
    gemm_nt_k<EpiSiluScatter><<<g,256,0,stream>>>(t1, Wk, D_, EpiSiluScatter{qk, 1});
    gemm_nt_k<EpiSiluScatter><<<g,256,0,stream>>>(xs, Wv, D_, EpiSiluScatter{vbuf, -1});
    gemm_nt_k<EpiSiluScatter><<<g,256,0,stream>>>(xr, Wq, D_, EpiSiluScatter{qk, 0});
  }
  // l2norm all q/k rows
  l2norm_k<<<N_*512,256,0,stream>>>(qk);
  // init memory state
  init_state_k<<<4096,256,0,stream>>>(W0, W1, W0c, W1c, S0m, S1m);

  // scan over chunks
  for (int t=0;t<N_;++t){
    const float* qkt = qk   + (size_t)t*512*D_;
    const float* vt  = vbuf + (size_t)t*256*D_;
    // S1: h = [q;k] @ W0^T ; a = silu(h)
    gemm_nt_k<EpiHA><<<dim3(D_/TN, 512/TM),256,0,stream>>>(qkt, W0c, D_, EpiHA{h, a});
    // S2: p = a @ W1^T ; rows<256 -> preout (retrieved), rows>=256 -> dpred
    gemm_nt_k<EpiRetr><<<dim3(D_/TN, 512/TM),256,0,stream>>>(a, W1c, D_, EpiRetr{preout, vt, dpred, t});
    // S3a: dh1 = (dpred @ W1) * silu'(h_k)     (reads W1c BEFORE update)
    gemm_nn_k<EpiDH><<<dim3(D_/TN, 256/TM),256,0,stream>>>(dpred, W1c, D_, D_, EpiDH{dh1, h + 256*D_});
    // S3b: g1 = dpred^T @ a_k ; fused S1m/W1c update
    gemm_tn_k<EpiUpd><<<dim3(D_/TN, D_/TM),256,0,stream>>>(dpred, a + 256*D_, 256, D_, D_, EpiUpd{W1c, S1m, gates, t});
    // S4: g0 = dh1^T @ k_t ; fused S0m/W0c update
    gemm_tn_k<EpiUpd><<<dim3(D_/TN, D_/TM),256,0,stream>>>(dh1, qkt + 256*D_, 256, D_, D_, EpiUpd{W0c, S0m, gates, t});
  }
  // F1: out = preout @ Wo^T
  gemm_nt_k<EpiStore><<<dim3(D_/TN, (B_*S_)/TM),256,0,stream>>>(preout, Wo, D_, EpiStore{out});
}

// Round 2
// 7453.186 us; speedup vs baseline: 1.0706x; 1.0706x over previous
//
#include <hip/hip_runtime.h>
#include <math.h>

static constexpr int B_ = 4, S_ = 2048, D_ = 1024, CH_ = 64, N_ = 32;
static constexpr float EPS_ = 1.1920929e-07f;
static constexpr float C2_  = 2.0f / 262144.0f;   // 2/(B*CH*D)

typedef __attribute__((ext_vector_type(8))) short bf16x8;
typedef __attribute__((ext_vector_type(4))) short bf16x4;
typedef __attribute__((ext_vector_type(4))) float f32x4;

__device__ __forceinline__ float sigf(float x)  { return 1.f/(1.f+expf(-x)); }
__device__ __forceinline__ float siluf(float x) { return x/(1.f+expf(-x)); }
__device__ __forceinline__ float silugrad(float x){
  float s = 1.f/(1.f+expf(-x));
  return s*(1.f + x*(1.f-s));
}
__device__ __forceinline__ short f2b(float f){
  union{float f;unsigned u;}c; c.f=f;
  unsigned u=c.u;
  return (short)((u + 0x7fffu + ((u>>16)&1u)) >> 16);   // RNE
}
__device__ __forceinline__ float b2f(short h){
  union{unsigned u;float f;}c; c.u=((unsigned)(unsigned short)h)<<16; return c.f;
}

// ---------------- epilogue functors (r = row, c = col, v = fp32 acc) ----------------
struct EpiOut { float* C;
  __device__ void operator()(int r,int c,float v) const { C[(size_t)r*D_+c]=v; } };

struct EpiStoreBf { short* C;
  __device__ void operator()(int r,int c,float v) const { C[(size_t)r*D_+c]=f2b(v); } };

struct EpiBiasSig { float* C; const float* bias;
  __device__ void operator()(int r,int c,float v) const {
    C[(size_t)r*D_+c] = sigf(v + bias[c]); } };

// scatter rows (b*S+s) -> chunk-major; part: -1 = v [N,256,D], 0 = q rows, 1 = k rows of qk [N,512,D]
struct EpiScat { short* dst; int part;
  __device__ void operator()(int r,int c,float v) const {
    int b = r >> 11, s = r & 2047, t = s >> 6, ch = s & 63;
    short sv = f2b(siluf(v));
    if (part < 0) dst[((size_t)t*256 +             b*64 + ch)*D_ + c] = sv;
    else          dst[((size_t)t*512 + part*256 + b*64 + ch)*D_ + c] = sv;
  } };

struct EpiHA { float* hk; short* a;   // h pre-act (k rows, fp32) + silu(h) bf16 (all rows)
  __device__ void operator()(int r,int c,float v) const {
    if (r >= 256) hk[(size_t)(r-256)*D_+c] = v;
    a[(size_t)r*D_+c] = f2b(siluf(v));
  } };

struct EpiRetr { short* preout; const short* vt; short* dpred; int t;
  __device__ void operator()(int r,int c,float v) const {
    if (r < 256) { int b=r>>6, ch=r&63;
      preout[((size_t)b*S_ + t*CH_ + ch)*D_ + c] = f2b(v); }
    else { size_t i=(size_t)(r-256)*D_+c; dpred[i] = f2b(C2_*(v - b2f(vt[i]))); }
  } };

struct EpiDH { short* dh; const float* hk;
  __device__ void operator()(int r,int c,float v) const {
    size_t i=(size_t)r*D_+c; dh[i] = f2b(v * silugrad(hk[i])); } };

// momentum + decayed weight update (fp32 master) + bf16 mirror refresh
struct EpiUpd { float* W; float* Sm; short* Wb; const float* gates; int t;
  __device__ void operator()(int r,int c,float v) const {
    float al=gates[t], th=gates[N_+t], et=gates[2*N_+t];
    size_t i=(size_t)r*D_+c;
    float s = et*Sm[i] - th*v;
    Sm[i] = s;
    float w = (1.f-al)*W[i] + s;
    W[i] = w; Wb[i] = f2b(w);
  } };

// ---------------- MFMA GEMM ----------------
// C[M,N] = sum_k Aop[m,k]*Bop[k,n]
// mode 0 operand: row-major [dim, K], staged via global_load_lds (linear LDS, stride 32)
// mode 1 operand: row-major [K, dim], reg-staged transposed into LDS (stride 36, b64 frag reads)
template<int AM, int BMD, int WMW, int WNW, class Epi>
__global__ __launch_bounds__(WMW*WNW*64)
void mgemm(const short* __restrict__ A, const short* __restrict__ Bm,
           int K, int lda, int ldb, Epi epi){
  constexpr int BMR = WMW*64, BNR = WNW*64, T = WMW*WNW*64;
  constexpr int LA = AM ? 36 : 32, LB = BMD ? 36 : 32;
  __shared__ short LdsA[BMR*LA];
  __shared__ short LdsB[BNR*LB];
  const int tid = threadIdx.x, lane = tid & 63, w = tid >> 6;
  const int wm = w / WNW, wn = w % WNW, lrow = lane & 15, lk8 = lane >> 4;
  const int bm0 = blockIdx.y*BMR, bn0 = blockIdx.x*BNR;
  f32x4 acc[4][4];
  #pragma unroll
  for (int i=0;i<4;++i)
    #pragma unroll
    for (int j=0;j<4;++j) acc[i][j] = (f32x4){0.f,0.f,0.f,0.f};

  for (int k0=0; k0<K; k0+=32){
    if constexpr (AM==0){
      constexpr int CHK = BMR*4;            // 16B chunks
      for (int i=tid; i<CHK; i+=T){
        const short* src = A + (size_t)(bm0 + (i>>2))*lda + k0 + ((i&3)<<3);
        __builtin_amdgcn_global_load_lds(
          (const __attribute__((address_space(1))) void*)src,
          (__attribute__((address_space(3))) void*)(LdsA + i*8), 16, 0, 0);
      }
    } else {
      constexpr int RB = BMR/8, CHK = 32*RB;
      for (int i=tid; i<CHK; i+=T){
        int kr = i/RB, mo = (i%RB)*8;
        bf16x8 v = *(const bf16x8*)(A + (size_t)(k0+kr)*lda + bm0 + mo);
        #pragma unroll
        for (int j=0;j<8;++j) LdsA[(mo+j)*36 + kr] = v[j];
      }
    }
    if constexpr (BMD==0){
      constexpr int CHK = BNR*4;
      for (int i=tid; i<CHK; i+=T){
        const short* src = Bm + (size_t)(bn0 + (i>>2))*ldb + k0 + ((i&3)<<3);
        __builtin_amdgcn_global_load_lds(
          (const __attribute__((address_space(1))) void*)src,
          (__attribute__((address_space(3))) void*)(LdsB + i*8), 16, 0, 0);
      }
    } else {
      constexpr int RB = BNR/8, CHK = 32*RB;
      for (int i=tid; i<CHK; i+=T){
        int kr = i/RB, no = (i%RB)*8;
        bf16x8 v = *(const bf16x8*)(Bm + (size_t)(k0+kr)*ldb + bn0 + no);
        #pragma unroll
        for (int j=0;j<8;++j) LdsB[(no+j)*36 + kr] = v[j];
      }
    }
    __syncthreads();   // drains vmcnt (global_load_lds) + lgkm (ds_write)

    bf16x8 af[4], bfr[4];
    #pragma unroll
    for (int mi=0;mi<4;++mi){
      int row = wm*64 + mi*16 + lrow;
      if constexpr (AM==0) af[mi] = *(const bf16x8*)(LdsA + row*32 + lk8*8);
      else {
        const short* p = LdsA + row*36 + lk8*8;
        bf16x4 lo = *(const bf16x4*)p, hi = *(const bf16x4*)(p+4);
        af[mi] = __builtin_shufflevector(lo, hi, 0,1,2,3,4,5,6,7);
      }
    }
    #pragma unroll
    for (int ni=0;ni<4;++ni){
      int row = wn*64 + ni*16 + lrow;
      if constexpr (BMD==0) bfr[ni] = *(const bf16x8*)(LdsB + row*32 + lk8*8);
      else {
        const short* p = LdsB + row*36 + lk8*8;
        bf16x4 lo = *(const bf16x4*)p, hi = *(const bf16x4*)(p+4);
        bfr[ni] = __builtin_shufflevector(lo, hi, 0,1,2,3,4,5,6,7);
      }
    }
    #pragma unroll
    for (int mi=0;mi<4;++mi)
      #pragma unroll
      for (int ni=0;ni<4;++ni)
        acc[mi][ni] = __builtin_amdgcn_mfma_f32_16x16x32_bf16(af[mi], bfr[ni], acc[mi][ni], 0,0,0);
    __syncthreads();
  }

  #pragma unroll
  for (int mi=0;mi<4;++mi)
    #pragma unroll
    for (int ni=0;ni<4;++ni)
      #pragma unroll
      for (int r=0;r<4;++r)
        epi(bm0 + wm*64 + mi*16 + lk8*4 + r, bn0 + wn*64 + ni*16 + lrow, acc[mi][ni][r]);
}

// ---------------- small kernels ----------------
__device__ __forceinline__ float block_sum(float v){
  #pragma unroll
  for (int o=32;o>0;o>>=1) v += __shfl_down(v,o,64);
  __shared__ float sm4[4];
  int lane = threadIdx.x & 63, w = threadIdx.x >> 6;
  if (lane==0) sm4[w]=v;
  __syncthreads();
  float r = sm4[0]+sm4[1]+sm4[2]+sm4[3];
  __syncthreads();
  return r;
}

__global__ void conv_k(const float* __restrict__ s, short* __restrict__ d, int n4){
  int i = blockIdx.x*256 + threadIdx.x;
  if (i >= n4) return;
  float4 v = ((const float4*)s)[i];
  bf16x4 o = { f2b(v.x), f2b(v.y), f2b(v.z), f2b(v.w) };
  ((bf16x4*)d)[i] = o;
}

__global__ void chunk_mean_k(const float* __restrict__ x, short* __restrict__ cm){
  int idx = blockIdx.x*256 + threadIdx.x;     // B*N*D = 131072
  int d  = idx & (D_-1);
  int bn = idx >> 10;
  int b = bn >> 5, n = bn & 31;
  const float* p = x + ((size_t)b*S_ + n*CH_)*D_ + d;
  float s = 0.f;
  for (int ch=0; ch<CH_; ++ch) s += p[(size_t)ch*D_];
  cm[idx] = f2b(s * (1.f/CH_));
}

__global__ void gate_reduce_k(const float* __restrict__ Z, float* __restrict__ outp, float scale){
  int n = blockIdx.x;
  float s = 0.f;
  for (int b=0;b<B_;++b){
    const float* row = Z + (size_t)(b*N_+n)*D_;
    for (int j=threadIdx.x; j<D_; j+=256) s += row[j];
  }
  float tot = block_sum(s);
  if (threadIdx.x==0) outp[n] = scale * tot / (float)(B_*D_);
}

__global__ void rmsnorm2_k(const float* __restrict__ x, const float* __restrict__ gs,
                           const float* __restrict__ gr, short* __restrict__ xs, short* __restrict__ xr){
  size_t row = blockIdx.x;
  const float* xp = x + row*D_;
  float s = 0.f;
  for (int j=threadIdx.x;j<D_;j+=256){ float v=xp[j]; s+=v*v; }
  float tot = block_sum(s);
  float rinv = rsqrtf(tot/(float)D_ + EPS_);
  for (int j=threadIdx.x;j<D_;j+=256){
    float v = xp[j]*rinv;
    xs[row*D_+j] = f2b(v*gs[j]);
    xr[row*D_+j] = f2b(v*gr[j]);
  }
}

__global__ void l2norm_b(short* __restrict__ qk){
  size_t row = blockIdx.x;
  short* p = qk + row*D_;
  float s = 0.f;
  for (int j=threadIdx.x;j<D_;j+=256){ float v=b2f(p[j]); s+=v*v; }
  float tot = block_sum(s);
  float inv = 1.f / fmaxf(sqrtf(tot), 1e-12f);
  for (int j=threadIdx.x;j<D_;j+=256) p[j] = f2b(b2f(p[j])*inv);
}

__global__ void init_state_k(const float* __restrict__ W0, const float* __restrict__ W1,
                             float* __restrict__ W0c, float* __restrict__ W1c,
                             float* __restrict__ S0, float* __restrict__ S1,
                             short* __restrict__ W0cb, short* __restrict__ W1cb){
  size_t i = (size_t)blockIdx.x*256 + threadIdx.x;
  float a0=W0[i], a1=W1[i];
  W0c[i]=a0; W1c[i]=a1; S0[i]=0.f; S1[i]=0.f;
  W0cb[i]=f2b(a0); W1cb[i]=f2b(a1);
}

// ---------------- host ----------------
extern "C" void kernel_launch(void* const* d_in, const int* in_sizes, int n_in,
                              void* d_out, int out_size, void* d_ws, size_t ws_size,
                              hipStream_t stream) {
  (void)in_sizes; (void)n_in; (void)out_size;
  const float* x    = (const float*)d_in[0];
  const float* Mmet = (const float*)d_in[1];
  const float* Wk   = (const float*)d_in[2];
  const float* Wv   = (const float*)d_in[3];
  const float* Wq   = (const float*)d_in[4];
  const float* Wo   = (const float*)d_in[5];
  const float* Wgd  = (const float*)d_in[6];
  const float* bgd  = (const float*)d_in[7];
  const float* Wgl  = (const float*)d_in[8];
  const float* bgl  = (const float*)d_in[9];
  const float* Wgm  = (const float*)d_in[10];
  const float* bgm  = (const float*)d_in[11];
  const float* g_store = (const float*)d_in[12];
  const float* g_retr  = (const float*)d_in[13];
  const float* W0   = (const float*)d_in[14];
  const float* W1   = (const float*)d_in[15];
  float* out = (float*)d_out;

  if (ws_size < 166000000ull) return;   // ~165.4 MB layout below
  short* qk    = (short*)d_ws;          // [N,512,D]  q rows 0..255, k rows 256..511 per chunk
  short* vbuf  = qk    + 16777216;      // [N,256,D]
  short* xs    = vbuf  + 8388608;       // [B*S,D]
  short* xr    = xs    + 8388608;
  short* t1    = xr    + 8388608;       // curved keys input
  short* preout= t1    + 8388608;
  short* cm    = preout+ 8388608;       // [128,D]
  short* Wkb   = cm    + 131072;
  short* Wvb   = Wkb   + 1048576;
  short* Wqb   = Wvb   + 1048576;
  short* Wob   = Wqb   + 1048576;
  short* Wgdb  = Wob   + 1048576;
  short* Wglb  = Wgdb  + 1048576;
  short* Wgmb  = Wglb  + 1048576;
  short* Mmetb = Wgmb  + 1048576;       // [B,D,D]
  short* W0cb  = Mmetb + 4194304;
  short* W1cb  = W0cb  + 1048576;
  short* abuf  = W1cb  + 1048576;       // [512,D]
  short* dpred = abuf  + 524288;        // [256,D]
  short* dh1   = dpred + 262144;        // [256,D]
  float* Zg    = (float*)(dh1 + 262144);// [128,D]
  float* gates = Zg    + 131072;        // [96]
  float* hk    = gates + 96;            // [256,D]
  float* W0c   = hk    + 262144;
  float* W1c   = W0c   + 1048576;
  float* S0m   = W1c   + 1048576;
  float* S1m   = S0m   + 1048576;

  // weight/metric bf16 conversions
  conv_k<<<1024,256,0,stream>>>(Wk,  Wkb,  262144);
  conv_k<<<1024,256,0,stream>>>(Wv,  Wvb,  262144);
  conv_k<<<1024,256,0,stream>>>(Wq,  Wqb,  262144);
  conv_k<<<1024,256,0,stream>>>(Wo,  Wob,  262144);
  conv_k<<<1024,256,0,stream>>>(Wgd, Wgdb, 262144);
  conv_k<<<1024,256,0,stream>>>(Wgl, Wglb, 262144);
  conv_k<<<1024,256,0,stream>>>(Wgm, Wgmb, 262144);
  conv_k<<<4096,256,0,stream>>>(Mmet, Mmetb, 1048576);
  init_state_k<<<4096,256,0,stream>>>(W0, W1, W0c, W1c, S0m, S1m, W0cb, W1cb);

  // chunk means + gates
  chunk_mean_k<<<512,256,0,stream>>>(x, cm);
  {
    dim3 g(8,2);
    mgemm<0,0,1,2,EpiBiasSig><<<g,128,0,stream>>>(cm, Wgdb, 1024,1024,1024, EpiBiasSig{Zg, bgd});
    gate_reduce_k<<<N_,256,0,stream>>>(Zg, gates + 0,    0.01f);   // MEM_DECAY
    mgemm<0,0,1,2,EpiBiasSig><<<g,128,0,stream>>>(cm, Wglb, 1024,1024,1024, EpiBiasSig{Zg, bgl});
    gate_reduce_k<<<N_,256,0,stream>>>(Zg, gates + N_,   0.1f);    // MEM_LR
    mgemm<0,0,1,2,EpiBiasSig><<<g,128,0,stream>>>(cm, Wgmb, 1024,1024,1024, EpiBiasSig{Zg, bgm});
    gate_reduce_k<<<N_,256,0,stream>>>(Zg, gates + 2*N_, 0.9f);    // MEM_MOM
  }
  // dual RMSNorm
  rmsnorm2_k<<<B_*S_,256,0,stream>>>(x, g_store, g_retr, xs, xr);
  // t1 = xs @ Mmet[b]   (B operand mode1: Mmet as [K=d][N=e])
  for (int b=0;b<B_;++b)
    mgemm<0,1,2,2,EpiStoreBf><<<dim3(8,16),256,0,stream>>>(
      xs + (size_t)b*S_*D_, Mmetb + (size_t)b*D_*D_, 1024,1024,1024,
      EpiStoreBf{t1 + (size_t)b*S_*D_});
  // k, v, q projections with silu + chunk scatter
  {
    dim3 g(8,64);
    mgemm<0,0,2,2,EpiScat><<<g,256,0,stream>>>(t1, Wkb, 1024,1024,1024, EpiScat{qk, 1});
    mgemm<0,0,2,2,EpiScat><<<g,256,0,stream>>>(xs, Wvb, 1024,1024,1024, EpiScat{vbuf,-1});
    mgemm<0,0,2,2,EpiScat><<<g,256,0,stream>>>(xr, Wqb, 1024,1024,1024, EpiScat{qk, 0});
  }
  l2norm_b<<<N_*512,256,0,stream>>>(qk);

  // scan over chunks
  for (int t=0;t<N_;++t){
    const short* qkt = qk   + (size_t)t*512*D_;
    const short* vt  = vbuf + (size_t)t*256*D_;
    // S1: h = [q;k] @ W0^T
    mgemm<0,0,1,2,EpiHA><<<dim3(8,8),128,0,stream>>>(qkt, W0cb, 1024,1024,1024, EpiHA{hk, abuf});
    // S2: pred = a @ W1^T  -> retrieve + dpred
    mgemm<0,0,1,2,EpiRetr><<<dim3(8,8),128,0,stream>>>(abuf, W1cb, 1024,1024,1024, EpiRetr{preout, vt, dpred, t});
    // S3a: dh1 = (dpred @ W1) * silu'(h_k)   (B mode1 = W1cb as [K=o][N=i])
    mgemm<0,1,1,2,EpiDH><<<dim3(8,4),128,0,stream>>>(dpred, W1cb, 1024,1024,1024, EpiDH{dh1, hk});
    // S3b: g1[o2][o] = sum_r dpred[r][o2] a_k[r][o]  (both mode1), fused W1 update
    mgemm<1,1,2,2,EpiUpd><<<dim3(8,8),256,0,stream>>>(dpred, abuf + 256*D_, 256,1024,1024, EpiUpd{W1c, S1m, W1cb, gates, t});
    // S4: g0[o][i] = sum_r dh1[r][o] k[r][i]  (both mode1), fused W0 update
    mgemm<1,1,2,2,EpiUpd><<<dim3(8,8),256,0,stream>>>(dh1, qkt + 256*D_, 256,1024,1024, EpiUpd{W0c, S0m, W0cb, gates, t});
  }
  // out = preout @ Wo^T
  mgemm<0,0,2,2,EpiOut><<<dim3(8,64),256,0,stream>>>(preout, Wob, 1024,1024,1024, EpiOut{out});
}